// Round 3
// baseline (16.616 us; speedup 1.0000x reference)
//
#include <hip/hip_runtime.h>
#include <math.h>

#define N2V 32
#define BLOCK 256
#define TPT 8                 // l-values per thread
#define CHUNK (BLOCK * TPT)   // 2048 l per block

__global__ __launch_bounds__(BLOCK) void s4d_vand_kernel(
    const float* __restrict__ C,          // (H, N2, 2)
    const float* __restrict__ log_dt,     // (H,)
    const float* __restrict__ log_A_real, // (H, N2)
    const float* __restrict__ A_imag,     // (H, N2)
    float* __restrict__ K,                // (H, L)
    int L, int chunks_per_h)
{
    // per-n: sInit = (x, y, Cr, Ci)
    // sM4[n][k] = (Re R^{2k}, -Im R^{2k}, Re R^{2k+1}, -Im R^{2k+1}), R = exp(dtA*BLOCK)
    __shared__ float4 sInit[N2V];
    __shared__ float4 sM4[N2V][TPT / 2];

    const int h     = blockIdx.x / chunks_per_h;
    const int chunk = (blockIdx.x % chunks_per_h) * CHUNK;
    const int t     = threadIdx.x;

    if (t < N2V) {
        const int n = t;
        const float dt = expf(log_dt[h]);
        const float ar = -expf(log_A_real[h * N2V + n]);  // Re(A)
        const float ai = A_imag[h * N2V + n];             // Im(A)
        const float x = ar * dt;                          // Re(dtA)
        const float y = ai * dt;                          // Im(dtA)
        // w = exp(dtA) - 1
        float sn, cs;
        sincosf(y, &sn, &cs);
        const float e  = expf(x);
        const float wr = e * cs - 1.0f;
        const float wi = e * sn;
        // w / A = w * conj(A) / |A|^2
        const float inv = 1.0f / (ar * ar + ai * ai);
        const float dr = (wr * ar + wi * ai) * inv;
        const float di = (wi * ar - wr * ai) * inv;
        // Ceff = 2 * Cc * (w/A)
        const float cr = C[(h * N2V + n) * 2 + 0];
        const float ci = C[(h * N2V + n) * 2 + 1];
        const float Cr = 2.0f * (cr * dr - ci * di);
        const float Ci = 2.0f * (cr * di + ci * dr);
        sInit[n] = make_float4(x, y, Cr, Ci);
        // R = exp(dtA * BLOCK); table M[j] = R^j, store (Re, -Im) pairs packed 2/float4
        float sR, cR;
        sincosf(y * (float)BLOCK, &sR, &cR);
        const float eR = expf(x * (float)BLOCK);
        const float Rr = eR * cR;
        const float Ri = eR * sR;
        float mr = 1.0f, mi = 0.0f;
#pragma unroll
        for (int k = 0; k < TPT / 2; ++k) {
            const float m0r = mr, m0i = mi;
            const float m1r = mr * Rr - mi * Ri;
            const float m1i = mr * Ri + mi * Rr;
            sM4[n][k] = make_float4(m0r, -m0i, m1r, -m1i);
            mr = m1r * Rr - m1i * Ri;
            mi = m1r * Ri + m1i * Rr;
        }
    }
    __syncthreads();

    const int l0 = chunk + t;
    const float fl0 = (float)l0;

    float acc[TPT];
#pragma unroll
    for (int j = 0; j < TPT; ++j) acc[j] = 0.0f;

#pragma unroll 2
    for (int n = 0; n < N2V; ++n) {
        const float4 ini = sInit[n];                // broadcast ds_read_b128
        const float e = __expf(ini.x * fl0);
        float sn, cs;
        __sincosf(ini.y * fl0, &sn, &cs);
        const float br = e * cs, bi = e * sn;
        const float sr = ini.z * br - ini.w * bi;   // s0 = Ceff * r^l0
        const float si = ini.z * bi + ini.w * br;
#pragma unroll
        for (int k = 0; k < TPT / 2; ++k) {
            const float4 m = sM4[n][k];             // broadcast ds_read_b128
            acc[2 * k]     = fmaf(sr, m.x, fmaf(si, m.y, acc[2 * k]));
            acc[2 * k + 1] = fmaf(sr, m.z, fmaf(si, m.w, acc[2 * k + 1]));
        }
    }

    float* out = K + (size_t)h * L + l0;
#pragma unroll
    for (int j = 0; j < TPT; ++j) {
        const int l = l0 + j * BLOCK;
        if (l < L) out[(size_t)j * BLOCK] = acc[j];
    }
}

extern "C" void kernel_launch(void* const* d_in, const int* in_sizes, int n_in,
                              void* d_out, int out_size, void* d_ws, size_t ws_size,
                              hipStream_t stream) {
    // inputs: [0]=L (scalar), [1]=C (H,N2,2), [2]=log_dt (H,),
    //         [3]=log_A_real (H,N2), [4]=A_imag (H,N2)
    const float* C          = (const float*)d_in[1];
    const float* log_dt     = (const float*)d_in[2];
    const float* log_A_real = (const float*)d_in[3];
    const float* A_imag     = (const float*)d_in[4];
    float* K = (float*)d_out;

    const int H = in_sizes[2];            // log_dt has H elements
    const int L = out_size / H;           // output is (H, L)
    const int chunks_per_h = (L + CHUNK - 1) / CHUNK;

    dim3 grid(H * chunks_per_h);
    dim3 block(BLOCK);
    s4d_vand_kernel<<<grid, block, 0, stream>>>(C, log_dt, log_A_real, A_imag,
                                                K, L, chunks_per_h);
}